// Round 8
// baseline (597.673 us; speedup 1.0000x reference)
//
#include <hip/hip_runtime.h>

#define D 256
#define KCODES 8192
#define NTOK 16384
#define QSIZE (NTOK * D)
#define NBLK 128              // code blocks of 64 (screening granularity)
#define CBS 64                // codes per block
// TH: candidate window. R7 passed at 3e-4 with ~10-11 flagged blocks/token
// (measured via VALUBusy back-solve). +5e-5 absorbs bf16 storage of bmin
// (quantization <= 2e-5 each on bmin and rowmin).
#define TH 3.5e-4f

typedef short bf16x8 __attribute__((ext_vector_type(8)));   // 8 bf16 in 4 VGPRs
typedef float f32x4 __attribute__((ext_vector_type(4)));

#define P1_LDS (2 * 128 * 264 * 2)      // 135168 B: xsh+csh, [128][264] bf16 each
#define P2_LDS (256 * 65 * 4)           // 66560 B: fp32 cb transposed [k=256][65]

__device__ __forceinline__ ushort f32_to_bf16(float f) {
    unsigned u = __float_as_uint(f);
    return (ushort)((u + 0x7FFFu + ((u >> 16) & 1)) >> 16);
}
__device__ __forceinline__ float bf16_to_f32(ushort h) {
    return __uint_as_float((unsigned)h << 16);
}

// ---- convert fp32 -> bf16 (RNE), 4 elems/thread ----
__global__ __launch_bounds__(256) void cvt_kernel(const float* __restrict__ src,
                                                  ushort* __restrict__ dst) {
    int i = blockIdx.x * 256 + threadIdx.x;
    float4 v = reinterpret_cast<const float4*>(src)[i];
    ushort4 o;
    o.x = f32_to_bf16(v.x); o.y = f32_to_bf16(v.y);
    o.z = f32_to_bf16(v.z); o.w = f32_to_bf16(v.w);
    reinterpret_cast<ushort4*>(dst)[i] = o;
}

// ---- e2[c] = sum(cb[c,:]^2) fp32 exact; one wave per row ----
__global__ __launch_bounds__(256) void e2_kernel(const float* __restrict__ cb,
                                                 float* __restrict__ e2) {
    int c = blockIdx.x * 4 + (threadIdx.x >> 6);
    int lane = threadIdx.x & 63;
    float4 v = reinterpret_cast<const float4*>(cb + (size_t)c * D)[lane];
    float s = v.x * v.x + v.y * v.y + v.z * v.z + v.w * v.w;
#pragma unroll
    for (int off = 32; off > 0; off >>= 1) s += __shfl_down(s, off);
    if (lane == 0) e2[c] = s;
}

__global__ __launch_bounds__(256) void xsq_kernel(const float* __restrict__ x,
                                                  float* __restrict__ xsq) {
    int t = blockIdx.x * 4 + (threadIdx.x >> 6);
    int lane = threadIdx.x & 63;
    float4 v = reinterpret_cast<const float4*>(x + (size_t)t * D)[lane];
    float s = v.x * v.x + v.y * v.y + v.z * v.z + v.w * v.w;
#pragma unroll
    for (int off = 32; off > 0; off >>= 1) s += __shfl_down(s, off);
    if (lane == 0) xsq[t] = s;
}

// ---- Pass 1: bf16 MFMA screening GEMM ----
// d~ = e2[c] - 2*dot_bf16(x,cb); per-token min over each 64-code block,
// stored as bf16. Wave wc covers codes [n0+wc*64, n0+wc*64+64) -> its 16-lane
// min IS the 64-block min (no cross-wave combine needed).
__global__ __launch_bounds__(256) void pass1_kernel(
    const ushort* __restrict__ xb, const ushort* __restrict__ cbb,
    const float* __restrict__ e2, ushort* __restrict__ bmin) {
    extern __shared__ short sm[];
    short* xsh = sm;                 // [128][264]
    short* csh = sm + 128 * 264;     // [128][264]

    const int tid = threadIdx.x;
    const int w = tid >> 6, l = tid & 63;
    const int wr = w >> 1, wc = w & 1;
    const int t0 = blockIdx.x * 128, n0 = blockIdx.y * 128;

#pragma unroll
    for (int r = 0; r < 16; ++r) {
        int i = r * 256 + tid;
        int row = i >> 5, kp = i & 31;
        float4 vx = reinterpret_cast<const float4*>(xb + (size_t)(t0 + row) * D)[kp];
        *reinterpret_cast<float4*>(xsh + row * 264 + kp * 8) = vx;
        float4 vc = reinterpret_cast<const float4*>(cbb + (size_t)(n0 + row) * D)[kp];
        *reinterpret_cast<float4*>(csh + row * 264 + kp * 8) = vc;
    }
    __syncthreads();

    f32x4 acc[4][4];
#pragma unroll
    for (int mt = 0; mt < 4; ++mt)
#pragma unroll
        for (int nt = 0; nt < 4; ++nt) acc[mt][nt] = (f32x4)0.f;

    const short* xbase = xsh + (wr * 64 + (l & 15)) * 264 + (l >> 4) * 8;
    const short* cbase = csh + (wc * 64 + (l & 15)) * 264 + (l >> 4) * 8;
#pragma unroll
    for (int ks = 0; ks < 8; ++ks) {
        bf16x8 a[4], b[4];
#pragma unroll
        for (int mt = 0; mt < 4; ++mt)
            a[mt] = *reinterpret_cast<const bf16x8*>(xbase + mt * 16 * 264 + ks * 32);
#pragma unroll
        for (int nt = 0; nt < 4; ++nt)
            b[nt] = *reinterpret_cast<const bf16x8*>(cbase + nt * 16 * 264 + ks * 32);
#pragma unroll
        for (int mt = 0; mt < 4; ++mt)
#pragma unroll
            for (int nt = 0; nt < 4; ++nt)
                acc[mt][nt] = __builtin_amdgcn_mfma_f32_16x16x32_bf16(
                    a[mt], b[nt], acc[mt][nt], 0, 0, 0);
    }

    // epilogue: d~ = e2 - 2*acc; min over this wave's 64 codes per token row
    float e2v[4];
#pragma unroll
    for (int nt = 0; nt < 4; ++nt)
        e2v[nt] = e2[n0 + wc * 64 + nt * 16 + (l & 15)];
    const int nb64 = blockIdx.y * 2 + wc;
#pragma unroll
    for (int mt = 0; mt < 4; ++mt) {
#pragma unroll
        for (int r = 0; r < 4; ++r) {
            float dm = fmaf(-2.f, acc[mt][0][r], e2v[0]);
#pragma unroll
            for (int nt = 1; nt < 4; ++nt)
                dm = fminf(dm, fmaf(-2.f, acc[mt][nt][r], e2v[nt]));
#pragma unroll
            for (int off = 1; off < 16; off <<= 1)
                dm = fminf(dm, __shfl_xor(dm, off));
            if ((l & 15) == 0) {
                int token = t0 + wr * 64 + mt * 16 + (l >> 4) * 4 + r;
                bmin[(size_t)token * NBLK + nb64] = f32_to_bf16(dm);
            }
        }
    }
}

// ---- Pass 2a: per-token min over 128 bf16 block-mins; init bestKey ----
__global__ __launch_bounds__(256) void pass2a_kernel(
    const ushort* __restrict__ bmin, float* __restrict__ rowmin,
    unsigned long long* __restrict__ bestKey) {
    int t = blockIdx.x * 256 + threadIdx.x;
    const uint4* bm = reinterpret_cast<const uint4*>(bmin + (size_t)t * NBLK);
    float m = 3.4e38f;
#pragma unroll
    for (int i = 0; i < 16; ++i) {
        uint4 v = bm[i];
        unsigned a[4] = {v.x, v.y, v.z, v.w};
#pragma unroll
        for (int j = 0; j < 4; ++j) {
            m = fminf(m, __uint_as_float(a[j] << 16));
            m = fminf(m, __uint_as_float(a[j] & 0xFFFF0000u));
        }
    }
    rowmin[t] = m;
    bestKey[t] = 0xFFFFFFFFFFFFFFFFULL;
}

// ---- Pass 2b: exact fp32-chain rescan of candidate (token, 64-code-block) ----
// NUMERICS: identical to the R2-verified bit-exact path — single sequential
// fma chain k=0..255, d = fl(fl(xsq+e2) - 2*dot), ties -> smallest index.
// cb staged TRANSPOSED [k=256][65 pad] -> hot-loop reads lane-consecutive,
// conflict-free. 66.5 KB LDS -> 2 blocks/CU. Groups of 4 tokens per wave ->
// 4 independent fma chains per lane -> dependency latency issue-hidden.
__global__ __launch_bounds__(256, 2) void pass2b_kernel(
    const float* __restrict__ x, const float* __restrict__ cb,
    const float* __restrict__ e2, const float* __restrict__ xsq,
    const ushort* __restrict__ bmin, const float* __restrict__ rowmin,
    unsigned long long* __restrict__ bestKey) {
    extern __shared__ float csh2[];   // [256][65]
    const int tid = threadIdx.x;
    const int nb = blockIdx.x;        // 64-code block index

    // stage 64 cb rows transposed (coalesced reads; 8-way-banked writes, cold)
#pragma unroll
    for (int r = 0; r < 16; ++r) {
        int i = r * 256 + tid;
        int row = i >> 6, kq = i & 63;
        float4 v = reinterpret_cast<const float4*>(cb + (size_t)(nb * CBS + row) * D)[kq];
        csh2[(kq * 4 + 0) * 65 + row] = v.x;
        csh2[(kq * 4 + 1) * 65 + row] = v.y;
        csh2[(kq * 4 + 2) * 65 + row] = v.z;
        csh2[(kq * 4 + 3) * 65 + row] = v.w;
    }
    __syncthreads();

    const int w = tid >> 6, j = tid & 63;
    const int tb = blockIdx.y * 512 + w * 128;
    const float e2v = e2[nb * CBS + j];
    const int ci0 = nb * CBS + j;

    for (int c = 0; c < 2; ++c) {
        int t = tb + c * 64 + j;
        bool flag = bf16_to_f32(bmin[(size_t)t * NBLK + nb]) <= rowmin[t] + TH;
        unsigned long long mask = __ballot(flag);
        while (mask) {
            int tt[4], cnt = 0;
#pragma unroll
            for (int g = 0; g < 4; ++g) {
                if (mask) {
                    int b = __ffsll((long long)mask) - 1;
                    mask &= mask - 1;
                    tt[g] = tb + c * 64 + b;
                    ++cnt;
                } else {
                    tt[g] = tt[0];   // pad with duplicate (atomicMin idempotent)
                }
            }
            const float4* xr0 = reinterpret_cast<const float4*>(x + (size_t)tt[0] * D);
            const float4* xr1 = reinterpret_cast<const float4*>(x + (size_t)tt[1] * D);
            const float4* xr2 = reinterpret_cast<const float4*>(x + (size_t)tt[2] * D);
            const float4* xr3 = reinterpret_cast<const float4*>(x + (size_t)tt[3] * D);
            float a0 = 0.f, a1 = 0.f, a2 = 0.f, a3 = 0.f;
            for (int kq = 0; kq < 64; ++kq) {
                float4 x0 = xr0[kq], x1 = xr1[kq], x2 = xr2[kq], x3 = xr3[kq];
                float c0 = csh2[(kq * 4 + 0) * 65 + j];
                float c1 = csh2[(kq * 4 + 1) * 65 + j];
                float c2 = csh2[(kq * 4 + 2) * 65 + j];
                float c3 = csh2[(kq * 4 + 3) * 65 + j];
                a0 = fmaf(x0.x, c0, a0); a0 = fmaf(x0.y, c1, a0);
                a0 = fmaf(x0.z, c2, a0); a0 = fmaf(x0.w, c3, a0);
                a1 = fmaf(x1.x, c0, a1); a1 = fmaf(x1.y, c1, a1);
                a1 = fmaf(x1.z, c2, a1); a1 = fmaf(x1.w, c3, a1);
                a2 = fmaf(x2.x, c0, a2); a2 = fmaf(x2.y, c1, a2);
                a2 = fmaf(x2.z, c2, a2); a2 = fmaf(x2.w, c3, a2);
                a3 = fmaf(x3.x, c0, a3); a3 = fmaf(x3.y, c1, a3);
                a3 = fmaf(x3.z, c2, a3); a3 = fmaf(x3.w, c3, a3);
            }
            float av[4] = {a0, a1, a2, a3};
#pragma unroll
            for (int g = 0; g < 4; ++g) {
                float dd = fmaf(-2.f, av[g], xsq[tt[g]] + e2v);
                int ci = ci0;
#pragma unroll
                for (int off = 1; off < 64; off <<= 1) {
                    float od = __shfl_xor(dd, off);
                    int oc = __shfl_xor(ci, off);
                    if (od < dd || (od == dd && oc < ci)) { dd = od; ci = oc; }
                }
                if (j == 0) {
                    unsigned u = __float_as_uint(dd);
                    u = (u & 0x80000000u) ? ~u : (u | 0x80000000u);
                    unsigned long long key =
                        ((unsigned long long)u << 32) | (unsigned)ci;
                    atomicMin(bestKey + tt[g], key);
                }
            }
        }
    }
}

// ---- Pass 3: gather codebook row, emit quantized + idx + partial loss ----
__global__ __launch_bounds__(256) void gather_kernel(
    const float* __restrict__ x, const float* __restrict__ cb,
    const unsigned long long* __restrict__ bestKey,
    float* __restrict__ out, float* __restrict__ partial) {
    __shared__ float red[4];
    const int token = blockIdx.x;
    const int tid = threadIdx.x;
    const int idx = (int)(bestKey[token] & 0xFFFFFFFFULL);
    float q = cb[(size_t)idx * D + tid];
    float xv = x[(size_t)token * D + tid];
    out[(size_t)token * D + tid] = q;
    float d = q - xv;
    d = d * d;
#pragma unroll
    for (int off = 32; off > 0; off >>= 1) d += __shfl_down(d, off);
    if ((tid & 63) == 0) red[tid >> 6] = d;
    __syncthreads();
    if (tid == 0) {
        partial[token] = red[0] + red[1] + red[2] + red[3];
        out[(size_t)QSIZE + token] = (float)idx;
    }
}

__global__ __launch_bounds__(256) void loss_kernel(const float* __restrict__ partial,
                                                   float* __restrict__ out) {
    __shared__ float red[4];
    float s = 0.f;
    for (int i = threadIdx.x; i < NTOK; i += 256) s += partial[i];
#pragma unroll
    for (int off = 32; off > 0; off >>= 1) s += __shfl_down(s, off);
    if ((threadIdx.x & 63) == 0) red[threadIdx.x >> 6] = s;
    __syncthreads();
    if (threadIdx.x == 0) {
        float total = red[0] + red[1] + red[2] + red[3];
        out[(size_t)QSIZE + NTOK] = 0.25f * total / (float)QSIZE;
    }
}

extern "C" void kernel_launch(void* const* d_in, const int* in_sizes, int n_in,
                              void* d_out, int out_size, void* d_ws, size_t ws_size,
                              hipStream_t stream) {
    const float* x = (const float*)d_in[0];     // [16384, 256]
    const float* cb = (const float*)d_in[1];    // [8192, 256]
    float* out = (float*)d_out;
    float* ws = (float*)d_ws;

    // d_out doubles as scratch for passes 1-2 (fully overwritten by pass 3):
    //   [0, 8M): xb bf16 | [8M, 12M): cbb bf16 | [12M, 16M): bmin bf16 [NTOK][128]
    ushort* xb = (ushort*)d_out;
    ushort* cbb = (ushort*)((char*)d_out + 8388608);
    ushort* bmin = (ushort*)((char*)d_out + 12582912);

    // ws (floats): e2[8192] | xsq[16384] | rowmin[16384] | partial[16384] | bestKey u64[16384]
    float* e2 = ws;
    float* xsq = ws + 8192;
    float* rowmin = ws + 8192 + 16384;
    float* partial = ws + 8192 + 2 * 16384;
    unsigned long long* bestKey = (unsigned long long*)(ws + 8192 + 3 * 16384);

    hipFuncSetAttribute((const void*)pass1_kernel,
                        hipFuncAttributeMaxDynamicSharedMemorySize, P1_LDS);
    hipFuncSetAttribute((const void*)pass2b_kernel,
                        hipFuncAttributeMaxDynamicSharedMemorySize, P2_LDS);

    cvt_kernel<<<QSIZE / 1024, 256, 0, stream>>>(x, xb);
    cvt_kernel<<<KCODES * D / 1024, 256, 0, stream>>>(cb, cbb);
    e2_kernel<<<KCODES / 4, 256, 0, stream>>>(cb, e2);
    xsq_kernel<<<NTOK / 4, 256, 0, stream>>>(x, xsq);
    pass1_kernel<<<dim3(NTOK / 128, 64), 256, P1_LDS, stream>>>(xb, cbb, e2, bmin);
    pass2a_kernel<<<NTOK / 256, 256, 0, stream>>>(bmin, rowmin, bestKey);
    pass2b_kernel<<<dim3(NBLK, 32), 256, P2_LDS, stream>>>(
        x, cb, e2, xsq, bmin, rowmin, bestKey);
    gather_kernel<<<NTOK, 256, 0, stream>>>(x, cb, bestKey, out, partial);
    loss_kernel<<<1, 256, 0, stream>>>(partial, out);
}

// Round 12
// 547.781 us; speedup vs baseline: 1.0911x; 1.0911x over previous
//
#include <hip/hip_runtime.h>

#define D 256
#define KCODES 8192
#define NTOK 16384
#define QSIZE (NTOK * D)
#define NBLK 128              // screening blocks of 64 codes
#define CBS 64
// TH: candidate window. Budget (fp16 screen, cb pre-scaled 2^12 so no fp16
// subnormals): ref-rounding eta <= 3.05e-5 + 2*fp16-dot err (max-stat) ~2.4e-5
// + bf16 bmin quantization ~4e-6  => delta ~5.9e-5, need TH >= 2*delta ~1.2e-4.
// TH = 2e-4 gives ~1.7x margin. (Validated: R11 first-call passed bit-exact.)
#define TH 2e-4f
#define CBSCALE 4096.0f       // exact pow2; acc = 2^12 * dot
#define UNSCALE2 4.8828125e-4f // 2^-11 = 2 * 2^-12 (exact)

typedef _Float16 f16x8 __attribute__((ext_vector_type(8)));  // 8 fp16, 4 VGPRs
typedef float f32x4 __attribute__((ext_vector_type(4)));

#define P1_LDS (2 * 128 * 264 * 2)      // 135168 B: xsh+csh fp16 [128][264]
#define P2_LDS (256 * 65 * 4)           // 66560 B: cb^T fp32 [256][65] ONLY

__device__ __forceinline__ ushort f32_to_bf16(float f) {
    unsigned u = __float_as_uint(f);
    return (ushort)((u + 0x7FFFu + ((u >> 16) & 1)) >> 16);
}
__device__ __forceinline__ float bf16_to_f32(ushort h) {
    return __uint_as_float((unsigned)h << 16);
}
__device__ __forceinline__ ushort f32_to_f16(float f) {
    _Float16 h = (_Float16)f;          // v_cvt_f16_f32, RNE
    ushort u; __builtin_memcpy(&u, &h, 2);
    return u;
}
// race-free broadcast: v_readlane_b32 (register file, exec-independent)
__device__ __forceinline__ float rdlane(float v, int lane) {
    return __uint_as_float(__builtin_amdgcn_readlane(__float_as_uint(v), lane));
}

// ---- convert fp32 -> fp16 (RNE) with scale, 4 elems/thread ----
__global__ __launch_bounds__(256) void cvt16_kernel(const float* __restrict__ src,
                                                    ushort* __restrict__ dst,
                                                    float scale) {
    int i = blockIdx.x * 256 + threadIdx.x;
    float4 v = reinterpret_cast<const float4*>(src)[i];
    ushort4 o;
    o.x = f32_to_f16(v.x * scale); o.y = f32_to_f16(v.y * scale);
    o.z = f32_to_f16(v.z * scale); o.w = f32_to_f16(v.w * scale);
    reinterpret_cast<ushort4*>(dst)[i] = o;
}

// ---- e2[c] = sum(cb[c,:]^2) fp32 exact; one wave per row ----
__global__ __launch_bounds__(256) void e2_kernel(const float* __restrict__ cb,
                                                 float* __restrict__ e2) {
    int c = blockIdx.x * 4 + (threadIdx.x >> 6);
    int lane = threadIdx.x & 63;
    float4 v = reinterpret_cast<const float4*>(cb + (size_t)c * D)[lane];
    float s = v.x * v.x + v.y * v.y + v.z * v.z + v.w * v.w;
#pragma unroll
    for (int off = 32; off > 0; off >>= 1) s += __shfl_down(s, off);
    if (lane == 0) e2[c] = s;
}

__global__ __launch_bounds__(256) void xsq_kernel(const float* __restrict__ x,
                                                  float* __restrict__ xsq) {
    int t = blockIdx.x * 4 + (threadIdx.x >> 6);
    int lane = threadIdx.x & 63;
    float4 v = reinterpret_cast<const float4*>(x + (size_t)t * D)[lane];
    float s = v.x * v.x + v.y * v.y + v.z * v.z + v.w * v.w;
#pragma unroll
    for (int off = 32; off > 0; off >>= 1) s += __shfl_down(s, off);
    if (lane == 0) xsq[t] = s;
}

// ---- Pass 1: fp16 MFMA screening GEMM ----
// acc = 2^12 * dot(x, cb); d~ = e2 - 2^-11 * acc. Per-token min over each
// 64-code block stored as bf16. Fragment layouts dtype-independent (m89/m121).
__global__ __launch_bounds__(256) void pass1_kernel(
    const ushort* __restrict__ xb, const ushort* __restrict__ cbb,
    const float* __restrict__ e2, ushort* __restrict__ bmin) {
    extern __shared__ short sm[];
    short* xsh = sm;                 // [128][264] fp16 bits
    short* csh = sm + 128 * 264;     // [128][264]

    const int tid = threadIdx.x;
    const int w = tid >> 6, l = tid & 63;
    const int wr = w >> 1, wc = w & 1;
    const int t0 = blockIdx.x * 128, n0 = blockIdx.y * 128;

#pragma unroll
    for (int r = 0; r < 16; ++r) {
        int i = r * 256 + tid;
        int row = i >> 5, kp = i & 31;
        float4 vx = reinterpret_cast<const float4*>(xb + (size_t)(t0 + row) * D)[kp];
        *reinterpret_cast<float4*>(xsh + row * 264 + kp * 8) = vx;
        float4 vc = reinterpret_cast<const float4*>(cbb + (size_t)(n0 + row) * D)[kp];
        *reinterpret_cast<float4*>(csh + row * 264 + kp * 8) = vc;
    }
    __syncthreads();

    f32x4 acc[4][4];
#pragma unroll
    for (int mt = 0; mt < 4; ++mt)
#pragma unroll
        for (int nt = 0; nt < 4; ++nt) acc[mt][nt] = (f32x4)0.f;

    const short* xbase = xsh + (wr * 64 + (l & 15)) * 264 + (l >> 4) * 8;
    const short* cbase = csh + (wc * 64 + (l & 15)) * 264 + (l >> 4) * 8;
#pragma unroll
    for (int ks = 0; ks < 8; ++ks) {
        f16x8 a[4], b[4];
#pragma unroll
        for (int mt = 0; mt < 4; ++mt)
            a[mt] = *reinterpret_cast<const f16x8*>(xbase + mt * 16 * 264 + ks * 32);
#pragma unroll
        for (int nt = 0; nt < 4; ++nt)
            b[nt] = *reinterpret_cast<const f16x8*>(cbase + nt * 16 * 264 + ks * 32);
#pragma unroll
        for (int mt = 0; mt < 4; ++mt)
#pragma unroll
            for (int nt = 0; nt < 4; ++nt)
                acc[mt][nt] = __builtin_amdgcn_mfma_f32_16x16x32_f16(
                    a[mt], b[nt], acc[mt][nt], 0, 0, 0);
    }

    float e2v[4];
#pragma unroll
    for (int nt = 0; nt < 4; ++nt)
        e2v[nt] = e2[n0 + wc * 64 + nt * 16 + (l & 15)];
    const int nb64 = blockIdx.y * 2 + wc;
#pragma unroll
    for (int mt = 0; mt < 4; ++mt) {
#pragma unroll
        for (int r = 0; r < 4; ++r) {
            float dm = fmaf(-UNSCALE2, acc[mt][0][r], e2v[0]);
#pragma unroll
            for (int nt = 1; nt < 4; ++nt)
                dm = fminf(dm, fmaf(-UNSCALE2, acc[mt][nt][r], e2v[nt]));
#pragma unroll
            for (int off = 1; off < 16; off <<= 1)
                dm = fminf(dm, __shfl_xor(dm, off));
            if ((l & 15) == 0) {
                int token = t0 + wr * 64 + mt * 16 + (l >> 4) * 4 + r;
                bmin[(size_t)token * NBLK + nb64] = f32_to_bf16(dm);
            }
        }
    }
}

// ---- Pass 2a: per-token min over 128 bf16 block-mins; init bestKey ----
__global__ __launch_bounds__(256) void pass2a_kernel(
    const ushort* __restrict__ bmin, float* __restrict__ rowmin,
    unsigned long long* __restrict__ bestKey) {
    int t = blockIdx.x * 256 + threadIdx.x;
    const uint4* bm = reinterpret_cast<const uint4*>(bmin + (size_t)t * NBLK);
    float m = 3.4e38f;
#pragma unroll
    for (int i = 0; i < 16; ++i) {
        uint4 v = bm[i];
        unsigned a[4] = {v.x, v.y, v.z, v.w};
#pragma unroll
        for (int j = 0; j < 4; ++j) {
            m = fminf(m, __uint_as_float(a[j] << 16));
            m = fminf(m, __uint_as_float(a[j] & 0xFFFF0000u));
        }
    }
    rowmin[t] = m;
    bestKey[t] = 0xFFFFFFFFFFFFFFFFULL;
}

// ---- Pass 2b: exact fp32-chain rescan of candidates ----
// NUMERICS: identical to the R2-verified bit-exact path — single sequential
// fma chain k=0..255, d = fl(fl(xsq+e2) - 2*dot), ties -> smallest index.
// R12: NO cross-lane LDS staging (R11's ds_write->ds_read with only a
// wave_barrier is suspected racy). Lane j holds x[t][4j..4j+3] in a VGPR;
// the chain broadcasts x[t][k] via v_readlane (register file, race-free).
__global__ __launch_bounds__(256, 2) void pass2b_kernel(
    const float* __restrict__ x, const float* __restrict__ cb,
    const float* __restrict__ e2, const float* __restrict__ xsq,
    const ushort* __restrict__ bmin, const float* __restrict__ rowmin,
    unsigned long long* __restrict__ bestKey) {
    extern __shared__ float csh[];          // [256][65] cb^T fp32
    const int tid = threadIdx.x;
    const int nb = blockIdx.x;              // 64-code block

    // stage 64 cb rows transposed (coalesced reads; 8-way writes, one-time)
#pragma unroll
    for (int r = 0; r < 16; ++r) {
        int i = r * 256 + tid;
        int row = i >> 6, kq = i & 63;
        float4 v = reinterpret_cast<const float4*>(cb + (size_t)(nb * CBS + row) * D)[kq];
        csh[(kq * 4 + 0) * 65 + row] = v.x;
        csh[(kq * 4 + 1) * 65 + row] = v.y;
        csh[(kq * 4 + 2) * 65 + row] = v.z;
        csh[(kq * 4 + 3) * 65 + row] = v.w;
    }
    __syncthreads();

    const int w = tid >> 6, j = tid & 63;
    const float e2v = e2[nb * CBS + j];
    const int ci0 = nb * CBS + j;
    const int tb = blockIdx.y * 1024 + w * 256;

    for (int c = 0; c < 4; ++c) {
        int t = tb + c * 64 + j;
        bool flag = bf16_to_f32(bmin[(size_t)t * NBLK + nb]) <= rowmin[t] + TH;
        unsigned long long mask = __ballot(flag);
        while (mask) {
            int b0 = __ffsll((long long)mask) - 1; mask &= mask - 1;
            int b1 = b0;
            if (mask) { b1 = __ffsll((long long)mask) - 1; mask &= mask - 1; }
            const int t0 = tb + c * 64 + b0;
            const int t1 = tb + c * 64 + b1;
            // lane j holds x[t][4j..4j+3]; coalesced, one load per candidate
            float4 v0 = reinterpret_cast<const float4*>(x + (size_t)t0 * D)[j];
            float4 v1 = reinterpret_cast<const float4*>(x + (size_t)t1 * D)[j];
            float a0 = 0.f, a1 = 0.f;
            // k ascending, ONE fma chain per (token, code) — bit-compat order.
            // x[t][k] = readlane(v.comp[k&3], k>>2): pure register broadcast.
#pragma unroll
            for (int kq = 0; kq < 64; ++kq) {
                float c0 = csh[(kq * 4 + 0) * 65 + j];
                float c1 = csh[(kq * 4 + 1) * 65 + j];
                float c2 = csh[(kq * 4 + 2) * 65 + j];
                float c3 = csh[(kq * 4 + 3) * 65 + j];
                a0 = fmaf(rdlane(v0.x, kq), c0, a0);
                a0 = fmaf(rdlane(v0.y, kq), c1, a0);
                a0 = fmaf(rdlane(v0.z, kq), c2, a0);
                a0 = fmaf(rdlane(v0.w, kq), c3, a0);
                a1 = fmaf(rdlane(v1.x, kq), c0, a1);
                a1 = fmaf(rdlane(v1.y, kq), c1, a1);
                a1 = fmaf(rdlane(v1.z, kq), c2, a1);
                a1 = fmaf(rdlane(v1.w, kq), c3, a1);
            }
            float av[2] = {a0, a1};
            int tv[2] = {t0, t1};
#pragma unroll
            for (int g = 0; g < 2; ++g) {
                float dd = fmaf(-2.f, av[g], xsq[tv[g]] + e2v);
                int ci = ci0;
#pragma unroll
                for (int off = 1; off < 64; off <<= 1) {
                    float od = __shfl_xor(dd, off);
                    int oc = __shfl_xor(ci, off);
                    if (od < dd || (od == dd && oc < ci)) { dd = od; ci = oc; }
                }
                if (j == 0) {
                    unsigned u = __float_as_uint(dd);
                    u = (u & 0x80000000u) ? ~u : (u | 0x80000000u);
                    unsigned long long key =
                        ((unsigned long long)u << 32) | (unsigned)ci;
                    atomicMin(bestKey + tv[g], key);
                }
            }
        }
    }
}

// ---- Pass 3: gather codebook row, emit quantized + idx + partial loss ----
__global__ __launch_bounds__(256) void gather_kernel(
    const float* __restrict__ x, const float* __restrict__ cb,
    const unsigned long long* __restrict__ bestKey,
    float* __restrict__ out, float* __restrict__ partial) {
    __shared__ float red[4];
    const int token = blockIdx.x;
    const int tid = threadIdx.x;
    int idx = (int)(bestKey[token] & 0xFFFFFFFFULL);
    if ((unsigned)idx >= (unsigned)KCODES) idx = 0;  // defensive: no OOB access
    float q = cb[(size_t)idx * D + tid];
    float xv = x[(size_t)token * D + tid];
    out[(size_t)token * D + tid] = q;
    float d = q - xv;
    d = d * d;
#pragma unroll
    for (int off = 32; off > 0; off >>= 1) d += __shfl_down(d, off);
    if ((tid & 63) == 0) red[tid >> 6] = d;
    __syncthreads();
    if (tid == 0) {
        partial[token] = red[0] + red[1] + red[2] + red[3];
        out[(size_t)QSIZE + token] = (float)idx;
    }
}

__global__ __launch_bounds__(256) void loss_kernel(const float* __restrict__ partial,
                                                   float* __restrict__ out) {
    __shared__ float red[4];
    float s = 0.f;
    for (int i = threadIdx.x; i < NTOK; i += 256) s += partial[i];
#pragma unroll
    for (int off = 32; off > 0; off >>= 1) s += __shfl_down(s, off);
    if ((threadIdx.x & 63) == 0) red[threadIdx.x >> 6] = s;
    __syncthreads();
    if (threadIdx.x == 0) {
        float total = red[0] + red[1] + red[2] + red[3];
        out[(size_t)QSIZE + NTOK] = 0.25f * total / (float)QSIZE;
    }
}

extern "C" void kernel_launch(void* const* d_in, const int* in_sizes, int n_in,
                              void* d_out, int out_size, void* d_ws, size_t ws_size,
                              hipStream_t stream) {
    const float* x = (const float*)d_in[0];     // [16384, 256]
    const float* cb = (const float*)d_in[1];    // [8192, 256]
    float* out = (float*)d_out;
    float* ws = (float*)d_ws;

    // d_out doubles as scratch for passes 1-2 (fully overwritten by pass 3):
    //   [0, 8M): xb fp16 | [8M, 12M): bmin bf16 [NTOK][128] | [12M, 16M): cbb fp16
    ushort* xb = (ushort*)d_out;
    ushort* bmin = (ushort*)((char*)d_out + 8388608);
    ushort* cbb = (ushort*)((char*)d_out + 12582912);

    // ws (floats): e2[8192] | xsq[16384] | rowmin[16384] | partial[16384] | bestKey u64[16384]
    float* e2 = ws;
    float* xsq = ws + 8192;
    float* rowmin = ws + 8192 + 16384;
    float* partial = ws + 8192 + 2 * 16384;
    unsigned long long* bestKey = (unsigned long long*)(ws + 8192 + 3 * 16384);

    hipFuncSetAttribute((const void*)pass1_kernel,
                        hipFuncAttributeMaxDynamicSharedMemorySize, P1_LDS);
    hipFuncSetAttribute((const void*)pass2b_kernel,
                        hipFuncAttributeMaxDynamicSharedMemorySize, P2_LDS);

    cvt16_kernel<<<QSIZE / 1024, 256, 0, stream>>>(x, xb, 1.0f);
    cvt16_kernel<<<KCODES * D / 1024, 256, 0, stream>>>(cb, cbb, CBSCALE);
    e2_kernel<<<KCODES / 4, 256, 0, stream>>>(cb, e2);
    xsq_kernel<<<NTOK / 4, 256, 0, stream>>>(x, xsq);
    pass1_kernel<<<dim3(NTOK / 128, 64), 256, P1_LDS, stream>>>(xb, cbb, e2, bmin);
    pass2a_kernel<<<NTOK / 256, 256, 0, stream>>>(bmin, rowmin, bestKey);
    pass2b_kernel<<<dim3(NBLK, 16), 256, P2_LDS, stream>>>(
        x, cb, e2, xsq, bmin, rowmin, bestKey);
    gather_kernel<<<NTOK, 256, 0, stream>>>(x, cb, bestKey, out, partial);
    loss_kernel<<<1, 256, 0, stream>>>(partial, out);
}